// Round 11
// baseline (255.051 us; speedup 1.0000x reference)
//
#include <hip/hip_runtime.h>
#include <math.h>

// MaxMarginLoss: B=4,S=512,D=512,V=32000, gamma=0.5, eps=1e-12
// score[r,v] = (out_norm[r] - tgt_emb[r]) . voc_norm[v]  -> argmax_v (first-idx ties)
// loss = mean over non-pad rows of max(gamma + cos(out,voc[jmax]) - cos(out,voc[tgt]), 0)
//
// R11: fp8-e4m3 coarse GEMM (BK=128 bytes, 4 K-steps, XOR-8 swizzle, XCD strips,
// mfma_f32_16x16x32_fp8_fp8) + fp32 rescue: row_final rescores every tile-winner
// within 0.5 (=10 sigma of fp8 score error) of the coarse max using exact fp32
// dots (o.e_c and e_t.e_c from fp32 inputs), so argmax precision is restored.

#define Bb 4
#define Ss 512
#define Dd 512
#define Vv 32000
#define ROWS (Bb * Ss)          // 2048
#define NTILE_M (ROWS / 128)    // 16
#define NTILE_N (Vv / 128)      // 250
#define VOC_BLOCKS (Vv / 4)     // 8000

typedef __attribute__((ext_vector_type(4))) float f32x4;

__device__ __forceinline__ float waveReduceSum(float x) {
#pragma unroll
  for (int m = 32; m >= 1; m >>= 1) x += __shfl_xor(x, m, 64);
  return x;
}

__device__ __forceinline__ float waveReduceMax(float x) {
#pragma unroll
  for (int m = 32; m >= 1; m >>= 1) x = fmaxf(x, __shfl_xor(x, m, 64));
  return x;
}

// float -> fp8 e4m3 (OCP on gfx950), low byte of packed convert
__device__ __forceinline__ unsigned char f2e4m3(float f) {
  int p = __builtin_amdgcn_cvt_pk_fp8_f32(f, f, 0, false);
  return (unsigned char)(p & 0xff);
}

__device__ __forceinline__ void async_ld16(const void* g, void* l) {
  __builtin_amdgcn_global_load_lds((const __attribute__((address_space(1))) void*)g,
                                   (__attribute__((address_space(3))) void*)l, 16, 0, 0);
}

// K1: fused prep. blocks [0,8000): 4 vocab rows -> e8 (normalized, fp8) + inv_norm.
//     blocks [8000,10048): ONE preds row -> o_rows(f32), u8(fp8), cos_tgt(f32).
__global__ __launch_bounds__(256) void prep_all(
    const float* __restrict__ preds, const float* __restrict__ emb,
    const int* __restrict__ target,
    float* __restrict__ o_rows, unsigned char* __restrict__ u8,
    float* __restrict__ cos_tgt, unsigned char* __restrict__ e8,
    float* __restrict__ inv_norm) {
  int tid = threadIdx.x;
  int wave = tid >> 6, lane = tid & 63;
  if (blockIdx.x < VOC_BLOCKS) {
    int v = blockIdx.x * 4 + wave;
    const float* e = emb + (size_t)v * Dd;
    float4 x0 = *(const float4*)(e + lane * 8);
    float4 x1 = *(const float4*)(e + lane * 8 + 4);
    float ss = x0.x * x0.x + x0.y * x0.y + x0.z * x0.z + x0.w * x0.w +
               x1.x * x1.x + x1.y * x1.y + x1.z * x1.z + x1.w * x1.w;
    ss = waveReduceSum(ss);
    float inv = 1.0f / fmaxf(sqrtf(ss), 1e-12f);
    int lo = __builtin_amdgcn_cvt_pk_fp8_f32(x0.x * inv, x0.y * inv, 0, false);
    lo = __builtin_amdgcn_cvt_pk_fp8_f32(x0.z * inv, x0.w * inv, lo, true);
    int hi = __builtin_amdgcn_cvt_pk_fp8_f32(x1.x * inv, x1.y * inv, 0, false);
    hi = __builtin_amdgcn_cvt_pk_fp8_f32(x1.z * inv, x1.w * inv, hi, true);
    int2 pk = make_int2(lo, hi);
    *(int2*)(e8 + (size_t)v * Dd + lane * 8) = pk;
    if (lane == 0) inv_norm[v] = inv;
  } else {
    int row = blockIdx.x - VOC_BLOCKS;
    int b = row >> 9, s = row & (Ss - 1);
    const float* p = preds + (size_t)b * Dd * Ss + s;
    float x0 = p[(size_t)tid * Ss];
    float x1 = p[(size_t)(tid + 256) * Ss];
    __shared__ float red[12];
    float ss = waveReduceSum(x0 * x0 + x1 * x1);
    if (lane == 0) red[wave] = ss;
    __syncthreads();
    float inv = 1.0f / fmaxf(sqrtf(red[0] + red[1] + red[2] + red[3]), 1e-12f);
    float o0 = x0 * inv, o1 = x1 * inv;
    o_rows[(size_t)row * Dd + tid] = o0;
    o_rows[(size_t)row * Dd + tid + 256] = o1;
    int t = target[row];
    const float* et = emb + (size_t)t * Dd;
    float e0 = et[tid], e1 = et[tid + 256];
    u8[(size_t)row * Dd + tid] = f2e4m3(o0 - e0);
    u8[(size_t)row * Dd + tid + 256] = f2e4m3(o1 - e1);
    float ss2 = waveReduceSum(e0 * e0 + e1 * e1);
    float dt = waveReduceSum(o0 * e0 + o1 * e1);
    if (lane == 0) { red[4 + wave] = ss2; red[8 + wave] = dt; }
    __syncthreads();
    if (tid == 0) {
      float n2 = red[4] + red[5] + red[6] + red[7];
      float dd = red[8] + red[9] + red[10] + red[11];
      cos_tgt[row] = dd * (1.0f / fmaxf(sqrtf(n2), 1e-12f));
    }
  }
}

// K2: 128x128-tile fp8 MFMA GEMM (B^T), BK=128 bytes (4 K-steps), XOR-8 bank
// swizzle, XCD strips, + coarse per-tile argmax epilogue (part_s/part_i).
// LDS row = 128 B = 8 x 16B chunks; logical chunk lc of row r at phys lc^(r&7).
__global__ __launch_bounds__(256, 4) void gemm_argmax(
    const unsigned char* __restrict__ u8, const unsigned char* __restrict__ e8,
    float* __restrict__ part_s, int* __restrict__ part_i) {
  __shared__ unsigned char sA[128 * 128];  // 16 KB
  __shared__ unsigned char sB[128 * 128];  // 16 KB
  int bid = blockIdx.x;
  int g = (bid & 7) * 500 + (bid >> 3);
  int tm = g & 15, tn = g >> 4;
  int tid = threadIdx.x;
  int w = tid >> 6, lane = tid & 63;
  int wm = w >> 1, wn = w & 1;

  // staging: glds dest = wave-base + lane*16 -> row = lane>>3, chunk = lane&7.
  // lane sources GLOBAL 16B chunk (lane&7)^((lane>>3)&7): phys chunk (lane&7)
  // of row r holds logical chunk (lane&7)^(r&7).
  int srow = w * 8 + (lane >> 3);
  int schunk = (lane & 7) ^ ((lane >> 3) & 7);
  const unsigned char* gA = u8 + (size_t)(tm * 128 + srow) * Dd + schunk * 16;
  const unsigned char* gB = e8 + (size_t)(tn * 128 + srow) * Dd + schunk * 16;

  // fragment read (mfma 16x16x32 fp8: row=lane&15, k=(lane>>4)*8+j):
  // per K-chunk kc (k=kc*32..+32): lane bytes at row-offset kc*32 + q*8,
  // q=lane>>4 -> logical 16B chunk 2*kc+(q>>1), byte-in-chunk (q&1)*8.
  int fr = lane & 15;
  int q = lane >> 4;
  int qh = q >> 1, ql = (q & 1) * 8;
  int flow = fr & 7;

  f32x4 acc[4][4];
  f32x4 z = {0.f, 0.f, 0.f, 0.f};
#pragma unroll
  for (int mi = 0; mi < 4; ++mi)
#pragma unroll
    for (int ni = 0; ni < 4; ++ni) acc[mi][ni] = z;

  for (int kk = 0; kk < 4; ++kk) {  // 4 K-steps of 128
    __syncthreads();  // previous compute done before overwrite
    {
      const unsigned char* ga = gA + kk * 128;
      const unsigned char* gb = gB + kk * 128;
#pragma unroll
      for (int i = 0; i < 4; ++i) {
        async_ld16(ga + (size_t)(i * 32) * Dd, &sA[(w * 8 + i * 32) * 128]);
        async_ld16(gb + (size_t)(i * 32) * Dd, &sB[(w * 8 + i * 32) * 128]);
      }
    }
    __syncthreads();  // staging visible (vmcnt drained by barrier)
#pragma unroll
    for (int kc = 0; kc < 4; ++kc) {
      int off = ((2 * kc + qh) ^ flow) * 16 + ql;
      long af[4], bg[4];
#pragma unroll
      for (int mi = 0; mi < 4; ++mi)
        af[mi] = *(const long*)(sA + (wm * 64 + mi * 16 + fr) * 128 + off);
#pragma unroll
      for (int ni = 0; ni < 4; ++ni)
        bg[ni] = *(const long*)(sB + (wn * 64 + ni * 16 + fr) * 128 + off);
#pragma unroll
      for (int mi = 0; mi < 4; ++mi)
#pragma unroll
        for (int ni = 0; ni < 4; ++ni)
          acc[mi][ni] = __builtin_amdgcn_mfma_f32_16x16x32_fp8_fp8(af[mi], bg[ni], acc[mi][ni], 0, 0, 0);
    }
  }

  // ---- coarse argmax epilogue ----
  // C layout: col = lane&15, row = (lane>>4)*4 + reg
  float bs[4][4];
  int bc[4][4];
  int col0 = tn * 128 + wn * 64 + (lane & 15);
#pragma unroll
  for (int mi = 0; mi < 4; ++mi) {
#pragma unroll
    for (int j = 0; j < 4; ++j) { bs[mi][j] = acc[mi][0][j]; bc[mi][j] = col0; }
#pragma unroll
    for (int ni = 1; ni < 4; ++ni) {
      int c = col0 + ni * 16;
#pragma unroll
      for (int j = 0; j < 4; ++j) {
        float v = acc[mi][ni][j];
        if (v > bs[mi][j]) { bs[mi][j] = v; bc[mi][j] = c; }
      }
    }
  }
#pragma unroll
  for (int m = 1; m < 16; m <<= 1) {
#pragma unroll
    for (int mi = 0; mi < 4; ++mi)
#pragma unroll
      for (int j = 0; j < 4; ++j) {
        float os = __shfl_xor(bs[mi][j], m, 64);
        int oc = __shfl_xor(bc[mi][j], m, 64);
        if (os > bs[mi][j] || (os == bs[mi][j] && oc < bc[mi][j])) {
          bs[mi][j] = os;
          bc[mi][j] = oc;
        }
      }
  }
  __syncthreads();  // done reading sA/sB; reuse as merge scratch
  float* sEs = (float*)sA;          // [2][128]
  int* sEc = (int*)sA + 256;        // [2][128]
  if ((lane & 15) == 0) {
    int qq = lane >> 4;
#pragma unroll
    for (int mi = 0; mi < 4; ++mi)
#pragma unroll
      for (int j = 0; j < 4; ++j) {
        int rloc = wm * 64 + mi * 16 + qq * 4 + j;
        sEs[wn * 128 + rloc] = bs[mi][j];
        sEc[wn * 128 + rloc] = bc[mi][j];
      }
  }
  __syncthreads();
  if (tid < 128) {
    float s0 = sEs[tid], s1 = sEs[128 + tid];
    int c0 = sEc[tid], c1 = sEc[128 + tid];
    if (s1 > s0 || (s1 == s0 && c1 < c0)) { s0 = s1; c0 = c1; }
    part_s[(size_t)tn * ROWS + tm * 128 + tid] = s0;
    part_i[(size_t)tn * ROWS + tm * 128 + tid] = c0;
  }
}

// K3: per row — fp32 rescue. Rescore all tile-winners within MARGIN of the
// coarse max using exact fp32 dots; pick fp32-argmax (ties -> smaller col),
// then hinge. One wave per row.
#define MARGIN 0.5f
__global__ __launch_bounds__(256) void row_final(
    const float* __restrict__ o_rows, const float* __restrict__ emb,
    const float* __restrict__ inv_norm, const float* __restrict__ cos_tgt,
    const int* __restrict__ target, const int* __restrict__ pad_id,
    const float* __restrict__ part_s, const int* __restrict__ part_i,
    float* __restrict__ diffs) {
  int wave = threadIdx.x >> 6, lane = threadIdx.x & 63;
  int row = blockIdx.x * 4 + wave;
  int tgt = target[row];
  const float* o = o_rows + (size_t)row * Dd;
  const float* et = emb + (size_t)tgt * Dd;
  float4 oa = *(const float4*)(o + lane * 8);
  float4 ob = *(const float4*)(o + lane * 8 + 4);
  float4 ta = *(const float4*)(et + lane * 8);
  float4 tb = *(const float4*)(et + lane * 8 + 4);

  float m = -INFINITY;
  for (int t = lane; t < NTILE_N; t += 64) m = fmaxf(m, part_s[(size_t)t * ROWS + row]);
  m = waveReduceMax(m);
  float thr = m - MARGIN;

  float bscore = -INFINITY;
  int bcol = 0x7fffffff;
  float bdo = 0.f;
  for (int t = 0; t < NTILE_N; ++t) {
    float s8 = part_s[(size_t)t * ROWS + row];  // same addr all lanes: broadcast
    if (s8 >= thr) {
      int c = part_i[(size_t)t * ROWS + row];
      const float* ec = emb + (size_t)c * Dd;
      float4 ea = *(const float4*)(ec + lane * 8);
      float4 eb = *(const float4*)(ec + lane * 8 + 4);
      float po = oa.x * ea.x + oa.y * ea.y + oa.z * ea.z + oa.w * ea.w +
                 ob.x * eb.x + ob.y * eb.y + ob.z * eb.z + ob.w * eb.w;
      float pt = ta.x * ea.x + ta.y * ea.y + ta.z * ea.z + ta.w * ea.w +
                 tb.x * eb.x + tb.y * eb.y + tb.z * eb.z + tb.w * eb.w;
      po = waveReduceSum(po);
      pt = waveReduceSum(pt);
      float sc = (po - pt) * inv_norm[c];
      if (sc > bscore || (sc == bscore && c < bcol)) {
        bscore = sc;
        bcol = c;
        bdo = po;
      }
    }
  }
  if (lane == 0) {
    float cmax = bdo * inv_norm[bcol];
    float df = fmaxf(0.5f + cmax - cos_tgt[row], 0.0f);
    diffs[row] = (tgt != pad_id[0]) ? df : 0.0f;
  }
}

// F: masked mean.
__global__ __launch_bounds__(256) void reduce_final(
    const float* __restrict__ diffs, const int* __restrict__ target,
    const int* __restrict__ pad_id, float* __restrict__ out) {
  int tid = threadIdx.x;
  int pid = pad_id[0];
  float s = 0.f, c = 0.f;
  for (int i = tid; i < ROWS; i += 256) {
    s += diffs[i];
    c += (target[i] != pid) ? 1.0f : 0.0f;
  }
  s = waveReduceSum(s);
  c = waveReduceSum(c);
  __shared__ float rs[4], rc[4];
  int wave = tid >> 6, lane = tid & 63;
  if (lane == 0) { rs[wave] = s; rc[wave] = c; }
  __syncthreads();
  if (tid == 0) out[0] = (rs[0] + rs[1] + rs[2] + rs[3]) / (rc[0] + rc[1] + rc[2] + rc[3]);
}

extern "C" void kernel_launch(void* const* d_in, const int* in_sizes, int n_in,
                              void* d_out, int out_size, void* d_ws, size_t ws_size,
                              hipStream_t stream) {
  const float* preds = (const float*)d_in[0];
  const float* emb = (const float*)d_in[1];
  const int* target = (const int*)d_in[2];
  const int* pad_id = (const int*)d_in[3];
  char* ws = (char*)d_ws;
  // ws layout (bytes), total ~25.6 MB
  float* o_rows = (float*)ws;                          // 2048*512*4 = 4,194,304
  unsigned char* u8 = (unsigned char*)(ws + 4194304);  // 2048*512   = 1,048,576
  unsigned char* e8 = (unsigned char*)(ws + 5242880);  // 32000*512  = 16,384,000
  float* inv_norm = (float*)(ws + 21626880);           // 32000*4    = 128,000
  float* cos_tgt = (float*)(ws + 21754880);            // 2048*4     = 8,192
  float* part_s = (float*)(ws + 21763072);             // 250*2048*4 = 2,048,000
  int* part_i = (int*)(ws + 23811072);                 // 250*2048*4 = 2,048,000
  float* diffs = (float*)(ws + 25859072);              // 2048*4

  prep_all<<<VOC_BLOCKS + ROWS, 256, 0, stream>>>(preds, emb, target, o_rows, u8,
                                                  cos_tgt, e8, inv_norm);
  gemm_argmax<<<NTILE_M * NTILE_N, 256, 0, stream>>>(u8, e8, part_s, part_i);
  row_final<<<ROWS / 4, 256, 0, stream>>>(o_rows, emb, inv_norm, cos_tgt, target,
                                          pad_id, part_s, part_i, diffs);
  reduce_final<<<1, 256, 0, stream>>>(diffs, target, pad_id, (float*)d_out);
}

// Round 12
// 191.390 us; speedup vs baseline: 1.3326x; 1.3326x over previous
//
#include <hip/hip_runtime.h>
#include <math.h>

// MaxMarginLoss: B=4,S=512,D=512,V=32000, gamma=0.5, eps=1e-12
// score[r,v] = (out_norm[r] - tgt_emb[r]) . voc_norm[v]  -> argmax_v (first-idx ties)
// loss = mean over non-pad rows of max(gamma + cos(out,voc[jmax]) - cos(out,voc[tgt]), 0)
//
// R12 = R11 gemm (fp8 coarse, 81 us, untouched) + parallel fp32 rescue:
//  - gemm partials stored row-major -> coalesced rescue reads
//  - row_final: 1 block/row; block-max, LDS candidate list, 4 waves rescore
//    candidates cooperatively (was: serialized 250-iter broadcast loop).

#define Bb 4
#define Ss 512
#define Dd 512
#define Vv 32000
#define ROWS (Bb * Ss)          // 2048
#define NTILE_M (ROWS / 128)    // 16
#define NTILE_N (Vv / 128)      // 250
#define VOC_BLOCKS (Vv / 4)     // 8000
#define MARGIN 0.5f

typedef __attribute__((ext_vector_type(4))) float f32x4;

__device__ __forceinline__ float waveReduceSum(float x) {
#pragma unroll
  for (int m = 32; m >= 1; m >>= 1) x += __shfl_xor(x, m, 64);
  return x;
}

__device__ __forceinline__ float waveReduceMax(float x) {
#pragma unroll
  for (int m = 32; m >= 1; m >>= 1) x = fmaxf(x, __shfl_xor(x, m, 64));
  return x;
}

// float -> fp8 e4m3 (OCP on gfx950), low byte of packed convert
__device__ __forceinline__ unsigned char f2e4m3(float f) {
  int p = __builtin_amdgcn_cvt_pk_fp8_f32(f, f, 0, false);
  return (unsigned char)(p & 0xff);
}

__device__ __forceinline__ void async_ld16(const void* g, void* l) {
  __builtin_amdgcn_global_load_lds((const __attribute__((address_space(1))) void*)g,
                                   (__attribute__((address_space(3))) void*)l, 16, 0, 0);
}

// K1: fused prep. blocks [0,8000): 4 vocab rows -> e8 (normalized, fp8) + inv_norm.
//     blocks [8000,10048): ONE preds row -> o_rows(f32), u8(fp8), cos_tgt(f32).
__global__ __launch_bounds__(256) void prep_all(
    const float* __restrict__ preds, const float* __restrict__ emb,
    const int* __restrict__ target,
    float* __restrict__ o_rows, unsigned char* __restrict__ u8,
    float* __restrict__ cos_tgt, unsigned char* __restrict__ e8,
    float* __restrict__ inv_norm) {
  int tid = threadIdx.x;
  int wave = tid >> 6, lane = tid & 63;
  if (blockIdx.x < VOC_BLOCKS) {
    int v = blockIdx.x * 4 + wave;
    const float* e = emb + (size_t)v * Dd;
    float4 x0 = *(const float4*)(e + lane * 8);
    float4 x1 = *(const float4*)(e + lane * 8 + 4);
    float ss = x0.x * x0.x + x0.y * x0.y + x0.z * x0.z + x0.w * x0.w +
               x1.x * x1.x + x1.y * x1.y + x1.z * x1.z + x1.w * x1.w;
    ss = waveReduceSum(ss);
    float inv = 1.0f / fmaxf(sqrtf(ss), 1e-12f);
    int lo = __builtin_amdgcn_cvt_pk_fp8_f32(x0.x * inv, x0.y * inv, 0, false);
    lo = __builtin_amdgcn_cvt_pk_fp8_f32(x0.z * inv, x0.w * inv, lo, true);
    int hi = __builtin_amdgcn_cvt_pk_fp8_f32(x1.x * inv, x1.y * inv, 0, false);
    hi = __builtin_amdgcn_cvt_pk_fp8_f32(x1.z * inv, x1.w * inv, hi, true);
    int2 pk = make_int2(lo, hi);
    *(int2*)(e8 + (size_t)v * Dd + lane * 8) = pk;
    if (lane == 0) inv_norm[v] = inv;
  } else {
    int row = blockIdx.x - VOC_BLOCKS;
    int b = row >> 9, s = row & (Ss - 1);
    const float* p = preds + (size_t)b * Dd * Ss + s;
    float x0 = p[(size_t)tid * Ss];
    float x1 = p[(size_t)(tid + 256) * Ss];
    __shared__ float red[12];
    float ss = waveReduceSum(x0 * x0 + x1 * x1);
    if (lane == 0) red[wave] = ss;
    __syncthreads();
    float inv = 1.0f / fmaxf(sqrtf(red[0] + red[1] + red[2] + red[3]), 1e-12f);
    float o0 = x0 * inv, o1 = x1 * inv;
    o_rows[(size_t)row * Dd + tid] = o0;
    o_rows[(size_t)row * Dd + tid + 256] = o1;
    int t = target[row];
    const float* et = emb + (size_t)t * Dd;
    float e0 = et[tid], e1 = et[tid + 256];
    u8[(size_t)row * Dd + tid] = f2e4m3(o0 - e0);
    u8[(size_t)row * Dd + tid + 256] = f2e4m3(o1 - e1);
    float ss2 = waveReduceSum(e0 * e0 + e1 * e1);
    float dt = waveReduceSum(o0 * e0 + o1 * e1);
    if (lane == 0) { red[4 + wave] = ss2; red[8 + wave] = dt; }
    __syncthreads();
    if (tid == 0) {
      float n2 = red[4] + red[5] + red[6] + red[7];
      float dd = red[8] + red[9] + red[10] + red[11];
      cos_tgt[row] = dd * (1.0f / fmaxf(sqrtf(n2), 1e-12f));
    }
  }
}

// K2: 128x128-tile fp8 MFMA GEMM (B^T), BK=128 bytes (4 K-steps), XOR-8 bank
// swizzle, XCD strips, + coarse per-tile argmax epilogue. Partials row-major.
__global__ __launch_bounds__(256, 4) void gemm_argmax(
    const unsigned char* __restrict__ u8, const unsigned char* __restrict__ e8,
    float* __restrict__ part_s, int* __restrict__ part_i) {
  __shared__ unsigned char sA[128 * 128];  // 16 KB
  __shared__ unsigned char sB[128 * 128];  // 16 KB
  int bid = blockIdx.x;
  int g = (bid & 7) * 500 + (bid >> 3);
  int tm = g & 15, tn = g >> 4;
  int tid = threadIdx.x;
  int w = tid >> 6, lane = tid & 63;
  int wm = w >> 1, wn = w & 1;

  // staging: glds dest = wave-base + lane*16 -> row = lane>>3, chunk = lane&7.
  // lane sources GLOBAL 16B chunk (lane&7)^((lane>>3)&7): phys chunk (lane&7)
  // of row r holds logical chunk (lane&7)^(r&7).
  int srow = w * 8 + (lane >> 3);
  int schunk = (lane & 7) ^ ((lane >> 3) & 7);
  const unsigned char* gA = u8 + (size_t)(tm * 128 + srow) * Dd + schunk * 16;
  const unsigned char* gB = e8 + (size_t)(tn * 128 + srow) * Dd + schunk * 16;

  // fragment read (mfma 16x16x32 fp8: row=lane&15, k=(lane>>4)*8+j):
  // per K-chunk kc: lane bytes at row-offset kc*32 + q*8 -> logical 16B chunk
  // 2*kc+(q>>1), byte-in-chunk (q&1)*8; phys chunk = logical ^ (fr&7).
  int fr = lane & 15;
  int q = lane >> 4;
  int qh = q >> 1, ql = (q & 1) * 8;
  int flow = fr & 7;

  f32x4 acc[4][4];
  f32x4 z = {0.f, 0.f, 0.f, 0.f};
#pragma unroll
  for (int mi = 0; mi < 4; ++mi)
#pragma unroll
    for (int ni = 0; ni < 4; ++ni) acc[mi][ni] = z;

  for (int kk = 0; kk < 4; ++kk) {  // 4 K-steps of 128
    __syncthreads();  // previous compute done before overwrite
    {
      const unsigned char* ga = gA + kk * 128;
      const unsigned char* gb = gB + kk * 128;
#pragma unroll
      for (int i = 0; i < 4; ++i) {
        async_ld16(ga + (size_t)(i * 32) * Dd, &sA[(w * 8 + i * 32) * 128]);
        async_ld16(gb + (size_t)(i * 32) * Dd, &sB[(w * 8 + i * 32) * 128]);
      }
    }
    __syncthreads();  // staging visible (vmcnt drained by barrier)
#pragma unroll
    for (int kc = 0; kc < 4; ++kc) {
      int off = ((2 * kc + qh) ^ flow) * 16 + ql;
      long af[4], bg[4];
#pragma unroll
      for (int mi = 0; mi < 4; ++mi)
        af[mi] = *(const long*)(sA + (wm * 64 + mi * 16 + fr) * 128 + off);
#pragma unroll
      for (int ni = 0; ni < 4; ++ni)
        bg[ni] = *(const long*)(sB + (wn * 64 + ni * 16 + fr) * 128 + off);
#pragma unroll
      for (int mi = 0; mi < 4; ++mi)
#pragma unroll
        for (int ni = 0; ni < 4; ++ni)
          acc[mi][ni] = __builtin_amdgcn_mfma_f32_16x16x32_fp8_fp8(af[mi], bg[ni], acc[mi][ni], 0, 0, 0);
    }
  }

  // ---- coarse argmax epilogue ----
  // C layout: col = lane&15, row = (lane>>4)*4 + reg
  float bs[4][4];
  int bc[4][4];
  int col0 = tn * 128 + wn * 64 + (lane & 15);
#pragma unroll
  for (int mi = 0; mi < 4; ++mi) {
#pragma unroll
    for (int j = 0; j < 4; ++j) { bs[mi][j] = acc[mi][0][j]; bc[mi][j] = col0; }
#pragma unroll
    for (int ni = 1; ni < 4; ++ni) {
      int c = col0 + ni * 16;
#pragma unroll
      for (int j = 0; j < 4; ++j) {
        float v = acc[mi][ni][j];
        if (v > bs[mi][j]) { bs[mi][j] = v; bc[mi][j] = c; }
      }
    }
  }
#pragma unroll
  for (int m = 1; m < 16; m <<= 1) {
#pragma unroll
    for (int mi = 0; mi < 4; ++mi)
#pragma unroll
      for (int j = 0; j < 4; ++j) {
        float os = __shfl_xor(bs[mi][j], m, 64);
        int oc = __shfl_xor(bc[mi][j], m, 64);
        if (os > bs[mi][j] || (os == bs[mi][j] && oc < bc[mi][j])) {
          bs[mi][j] = os;
          bc[mi][j] = oc;
        }
      }
  }
  __syncthreads();  // done reading sA/sB; reuse as merge scratch
  float* sEs = (float*)sA;          // [2][128]
  int* sEc = (int*)sA + 256;        // [2][128]
  if ((lane & 15) == 0) {
    int qq = lane >> 4;
#pragma unroll
    for (int mi = 0; mi < 4; ++mi)
#pragma unroll
      for (int j = 0; j < 4; ++j) {
        int rloc = wm * 64 + mi * 16 + qq * 4 + j;
        sEs[wn * 128 + rloc] = bs[mi][j];
        sEc[wn * 128 + rloc] = bc[mi][j];
      }
  }
  __syncthreads();
  if (tid < 128) {
    float s0 = sEs[tid], s1 = sEs[128 + tid];
    int c0 = sEc[tid], c1 = sEc[128 + tid];
    if (s1 > s0 || (s1 == s0 && c1 < c0)) { s0 = s1; c0 = c1; }
    // row-major partials: coalesced reads in row_final
    part_s[(size_t)(tm * 128 + tid) * 256 + tn] = s0;
    part_i[(size_t)(tm * 128 + tid) * 256 + tn] = c0;
  }
}

// K3: parallel fp32 rescue. One block per row: coalesced partial read,
// block max, LDS candidate list (cols unique per tile), 4 waves rescore
// candidates cooperatively with exact fp32 dots, merge, hinge.
__global__ __launch_bounds__(256) void row_final(
    const float* __restrict__ o_rows, const float* __restrict__ emb,
    const float* __restrict__ inv_norm, const float* __restrict__ cos_tgt,
    const int* __restrict__ target, const int* __restrict__ pad_id,
    const float* __restrict__ part_s, const int* __restrict__ part_i,
    float* __restrict__ diffs) {
  int row = blockIdx.x;
  int tid = threadIdx.x;
  int w = tid >> 6, lane = tid & 63;
  __shared__ float sMax[4];
  __shared__ int sCand[256];
  __shared__ int sCnt;
  __shared__ float sBs[4], sBp[4];
  __shared__ int sBc[4];
  // phase 1: block max over the 250 tile partials (coalesced)
  float v = (tid < NTILE_N) ? part_s[(size_t)row * 256 + tid] : -INFINITY;
  float wmax = waveReduceMax(v);
  if (lane == 0) sMax[w] = wmax;
  if (tid == 0) sCnt = 0;
  __syncthreads();
  float thr = fmaxf(fmaxf(sMax[0], sMax[1]), fmaxf(sMax[2], sMax[3])) - MARGIN;
  // phase 2: candidate list (tile-winner cols are unique across tiles)
  if (tid < NTILE_N && v >= thr) {
    int idx = atomicAdd(&sCnt, 1);
    sCand[idx] = part_i[(size_t)row * 256 + tid];
  }
  __syncthreads();
  int n = sCnt;  // >= 1 (the max tile always qualifies)
  // per-lane row data
  int tgt = target[row];
  const float* o = o_rows + (size_t)row * Dd;
  const float* et = emb + (size_t)tgt * Dd;
  float4 oa = *(const float4*)(o + lane * 8);
  float4 ob = *(const float4*)(o + lane * 8 + 4);
  float4 ta = *(const float4*)(et + lane * 8);
  float4 tb = *(const float4*)(et + lane * 8 + 4);
  // phase 3: waves round-robin candidates
  float bscore = -INFINITY, bpo = 0.f;
  int bcol = 0x7fffffff;
  for (int i = w; i < n; i += 4) {
    int c = sCand[i];
    const float* ec = emb + (size_t)c * Dd;
    float4 ea = *(const float4*)(ec + lane * 8);
    float4 eb = *(const float4*)(ec + lane * 8 + 4);
    float po = oa.x * ea.x + oa.y * ea.y + oa.z * ea.z + oa.w * ea.w +
               ob.x * eb.x + ob.y * eb.y + ob.z * eb.z + ob.w * eb.w;
    float pt = ta.x * ea.x + ta.y * ea.y + ta.z * ea.z + ta.w * ea.w +
               tb.x * eb.x + tb.y * eb.y + tb.z * eb.z + tb.w * eb.w;
    po = waveReduceSum(po);
    pt = waveReduceSum(pt);
    float sc = (po - pt) * inv_norm[c];
    if (sc > bscore || (sc == bscore && c < bcol)) {
      bscore = sc;
      bcol = c;
      bpo = po;
    }
  }
  if (lane == 0) { sBs[w] = bscore; sBc[w] = bcol; sBp[w] = bpo; }
  __syncthreads();
  if (tid == 0) {
    float s = sBs[0], p = sBp[0];
    int c = sBc[0];
#pragma unroll
    for (int i = 1; i < 4; ++i)
      if (sBs[i] > s || (sBs[i] == s && sBc[i] < c)) { s = sBs[i]; c = sBc[i]; p = sBp[i]; }
    float cmax = p * inv_norm[c];
    float df = fmaxf(0.5f + cmax - cos_tgt[row], 0.0f);
    diffs[row] = (tgt != pad_id[0]) ? df : 0.0f;
  }
}

// F: masked mean.
__global__ __launch_bounds__(256) void reduce_final(
    const float* __restrict__ diffs, const int* __restrict__ target,
    const int* __restrict__ pad_id, float* __restrict__ out) {
  int tid = threadIdx.x;
  int pid = pad_id[0];
  float s = 0.f, c = 0.f;
  for (int i = tid; i < ROWS; i += 256) {
    s += diffs[i];
    c += (target[i] != pid) ? 1.0f : 0.0f;
  }
  s = waveReduceSum(s);
  c = waveReduceSum(c);
  __shared__ float rs[4], rc[4];
  int wave = tid >> 6, lane = tid & 63;
  if (lane == 0) { rs[wave] = s; rc[wave] = c; }
  __syncthreads();
  if (tid == 0) out[0] = (rs[0] + rs[1] + rs[2] + rs[3]) / (rc[0] + rc[1] + rc[2] + rc[3]);
}

extern "C" void kernel_launch(void* const* d_in, const int* in_sizes, int n_in,
                              void* d_out, int out_size, void* d_ws, size_t ws_size,
                              hipStream_t stream) {
  const float* preds = (const float*)d_in[0];
  const float* emb = (const float*)d_in[1];
  const int* target = (const int*)d_in[2];
  const int* pad_id = (const int*)d_in[3];
  char* ws = (char*)d_ws;
  // ws layout (bytes), total ~26 MB
  float* o_rows = (float*)ws;                          // 2048*512*4 = 4,194,304
  unsigned char* u8 = (unsigned char*)(ws + 4194304);  // 2048*512   = 1,048,576
  unsigned char* e8 = (unsigned char*)(ws + 5242880);  // 32000*512  = 16,384,000
  float* inv_norm = (float*)(ws + 21626880);           // 32000*4    = 128,000
  float* cos_tgt = (float*)(ws + 21754880);            // 2048*4     = 8,192
  float* part_s = (float*)(ws + 21763072);             // 2048*256*4 = 2,097,152
  int* part_i = (int*)(ws + 23860224);                 // 2048*256*4 = 2,097,152
  float* diffs = (float*)(ws + 25957376);              // 2048*4

  prep_all<<<VOC_BLOCKS + ROWS, 256, 0, stream>>>(preds, emb, target, o_rows, u8,
                                                  cos_tgt, e8, inv_norm);
  gemm_argmax<<<NTILE_M * NTILE_N, 256, 0, stream>>>(u8, e8, part_s, part_i);
  row_final<<<ROWS, 256, 0, stream>>>(o_rows, emb, inv_norm, cos_tgt, target,
                                      pad_id, part_s, part_i, diffs);
  reduce_final<<<1, 256, 0, stream>>>(diffs, target, pad_id, (float*)d_out);
}